// Round 11
// baseline (610.683 us; speedup 1.0000x reference)
//
#include <hip/hip_runtime.h>

// Problem constants (fixed by the reference)
constexpr int NN   = 100000;   // nodes
constexpr int EE   = 1600000;  // edges
constexpr int DIM  = 64;
constexpr int HH   = 4;        // heads
constexpr int CC   = 16;       // channels / head
constexpr int LL   = 3;        // layers
constexpr int GG   = 16;       // graphs
constexpr int NCLS = 2;
constexpr float SLOPE_ATT = 0.2f;
constexpr float SLOPE_ACT = 0.01f;
constexpr float EPS = 1e-5f;

constexpr int SCAN_CHUNK = 1024;
constexpr int NSCAN = (NN + SCAN_CHUNK - 1) / SCAN_CHUNK;   // 98
constexpr int NREP = 64;                                    // BN stat replicas

typedef int vint4 __attribute__((ext_vector_type(4)));
typedef float f32x2 __attribute__((ext_vector_type(2)));

__device__ __forceinline__ float lrelu_att(float v) { return v > 0.f ? v : SLOPE_ATT * v; }
__device__ __forceinline__ float lrelu_act(float v) { return v > 0.f ? v : SLOPE_ACT * v; }

// ---- CSR build: histogram of dst (int4, nontemporal) ----
__global__ __launch_bounds__(256) void k_hist(const int* __restrict__ ei,
                                              int* __restrict__ deg) {
    int i = blockIdx.x * 256 + threadIdx.x;
    if (i < EE / 4) {
        vint4 d = __builtin_nontemporal_load(&((const vint4*)(ei + EE))[i]);
        atomicAdd(&deg[d.x], 1);
        atomicAdd(&deg[d.y], 1);
        atomicAdd(&deg[d.z], 1);
        atomicAdd(&deg[d.w], 1);
    }
}

// ---- scan step 1: per-chunk exclusive scan + chunk totals ----
__global__ __launch_bounds__(256) void k_scan1(const int* __restrict__ deg,
                                               int* __restrict__ excl,
                                               int* __restrict__ bsum) {
    __shared__ int sh[256];
    const int b = blockIdx.x, t = threadIdx.x;
    const int i0 = b * SCAN_CHUNK + t * 4;
    int v[4];
#pragma unroll
    for (int i = 0; i < 4; ++i) v[i] = (i0 + i < NN) ? deg[i0 + i] : 0;
    int tsum = v[0] + v[1] + v[2] + v[3];
    sh[t] = tsum;
    __syncthreads();
    for (int o = 1; o < 256; o <<= 1) {
        int x = (t >= o) ? sh[t - o] : 0;
        __syncthreads();
        sh[t] += x;
        __syncthreads();
    }
    if (t == 255) bsum[b] = sh[255];
    int run = sh[t] - tsum;
#pragma unroll
    for (int i = 0; i < 4; ++i) {
        if (i0 + i < NN) excl[i0 + i] = run;
        run += v[i];
    }
}

// ---- scan steps 2+3 merged: per-block prefix of chunk totals + apply ----
__global__ __launch_bounds__(256) void k_scan23(int* __restrict__ row_start,
                                                const int* __restrict__ bsum,
                                                int* __restrict__ cursor) {
    __shared__ int sh[128];
    __shared__ int prefix;
    const int t = threadIdx.x;
    if (t < NSCAN) sh[t] = bsum[t];
    __syncthreads();
    if (t == 0) {
        int ci = blockIdx.x >> 2;           // 256 nodes/block, 1024/chunk
        int p = 0;
        for (int k = 0; k < ci; ++k) p += sh[k];
        prefix = p;
    }
    __syncthreads();
    int i = blockIdx.x * 256 + t;
    if (i < NN) {
        int v = row_start[i] + prefix;
        row_start[i] = v;
        cursor[i] = v;
    }
    if (i == 0) row_start[NN] = EE;
}

// ---- CSR fill, XCD-range partitioned, nontemporal ei streams ----
constexpr int FILL_NBLK = 512;
constexpr int DRANGE = (NN + 7) / 8;
__global__ __launch_bounds__(256) void k_fill(const int* __restrict__ ei,
                                              int* __restrict__ cursor,
                                              int* __restrict__ ssrc) {
    const int g = blockIdx.x & 7;
    const int blk = blockIdx.x >> 3;
    const int dlo = g * DRANGE, dhi = min(dlo + DRANGE, NN);
    const int stride = FILL_NBLK * 256;
    for (int e = blk * 256 + threadIdx.x; e < EE; e += stride) {
        int d = __builtin_nontemporal_load(&ei[EE + e]);
        if (d >= dlo && d < dhi) {
            int s = __builtin_nontemporal_load(&ei[e]);
            int pos = atomicAdd(&cursor[d], 1);
            ssrc[pos] = s;
        }
    }
}

// ---- GEMM, templated; h output packed fp8 e4m3 (4 channels / uint) ----
template<int MODE>
__global__ __launch_bounds__(256) void k_gemm_t(const float* __restrict__ xbase,
                                                const float* __restrict__ aggin,
                                                const float* __restrict__ scshf,
                                                const int* __restrict__ batch,
                                                const float* __restrict__ cntin,
                                                const float* __restrict__ Wl,
                                                const float* __restrict__ asrc,
                                                const float* __restrict__ adst,
                                                float* __restrict__ xcur_out,
                                                unsigned* __restrict__ h32,
                                                float* __restrict__ es,
                                                float* __restrict__ ed,
                                                double* __restrict__ bnrep,
                                                float* __restrict__ poolout,
                                                float* __restrict__ cntout) {
    if (blockIdx.x < NREP && threadIdx.x < 128)
        bnrep[(size_t)blockIdx.x * 128 + threadIdx.x] = 0.0;
    __shared__ float Ws[DIM][DIM];
    __shared__ float xsT[DIM][DIM];
    __shared__ float sp[GG * 64];
    __shared__ float scnt[GG];
    const int tid = threadIdx.x;
    const int row0 = blockIdx.x * 64;

    for (int i = tid; i < GG * 64; i += 256) sp[i] = 0.f;
    if (MODE == 0 && tid < GG) scnt[tid] = 0.f;
    __syncthreads();

    const float4* W4 = (const float4*)Wl;
#pragma unroll
    for (int i = 0; i < 4; ++i) ((float4*)Ws)[tid + 256 * i] = W4[tid + 256 * i];

    const int c4_ = tid & 15;
    float4 scv, shfv;
    if (MODE == 1) {
        scv  = ((const float4*)scshf)[c4_];
        shfv = ((const float4*)scshf)[16 + c4_];
    }

#pragma unroll
    for (int i = 0; i < 4; ++i) {
        int idx4 = tid + 256 * i;
        int r = idx4 >> 4, c4 = idx4 & 15;
        int grow = row0 + r;
        float4 v4 = make_float4(0.f, 0.f, 0.f, 0.f);
        if (grow < NN) {
            if (MODE == 0) {
                v4 = ((const float4*)xbase)[grow * 16 + c4];
                int g = batch[grow];
                atomicAdd(&sp[g * 64 + c4 * 4 + 0], v4.x);
                atomicAdd(&sp[g * 64 + c4 * 4 + 1], v4.y);
                atomicAdd(&sp[g * 64 + c4 * 4 + 2], v4.z);
                atomicAdd(&sp[g * 64 + c4 * 4 + 3], v4.w);
                if (c4 == 0) atomicAdd(&scnt[g], 1.f);
            } else {
                float4 a4 = ((const float4*)aggin)[grow * 16 + c4];
                float4 xb = ((const float4*)xbase)[grow * 16 + c4];
                int g = batch[grow];
                float rinv = rsqrtf(cntin[g]);
                float vx = lrelu_act((a4.x * scv.x + shfv.x) * rinv);
                float vy = lrelu_act((a4.y * scv.y + shfv.y) * rinv);
                float vz = lrelu_act((a4.z * scv.z + shfv.z) * rinv);
                float vw = lrelu_act((a4.w * scv.w + shfv.w) * rinv);
                atomicAdd(&sp[g * 64 + c4 * 4 + 0], vx);
                atomicAdd(&sp[g * 64 + c4 * 4 + 1], vy);
                atomicAdd(&sp[g * 64 + c4 * 4 + 2], vz);
                atomicAdd(&sp[g * 64 + c4 * 4 + 3], vw);
                v4 = make_float4(xb.x + vx, xb.y + vy, xb.z + vz, xb.w + vw);
                ((float4*)xcur_out)[grow * 16 + c4] = v4;
            }
        }
        int col = (((r >> 2) ^ c4) << 2) | (r & 3);
        xsT[c4 * 4 + 0][col] = v4.x;
        xsT[c4 * 4 + 1][col] = v4.y;
        xsT[c4 * 4 + 2][col] = v4.z;
        xsT[c4 * 4 + 3][col] = v4.w;
    }
    __syncthreads();

    const int tc = tid & 15, tr = tid >> 4;
    float acc[4][4] = {};
#pragma unroll 8
    for (int k = 0; k < DIM; ++k) {
        int kc = (k >> 2) & 15;
        float4 wv = *(const float4*)(&Ws[k][tc * 4]);
        float4 xv = *(const float4*)(&xsT[k][(tr ^ kc) * 4]);
        acc[0][0] = fmaf(xv.x, wv.x, acc[0][0]);
        acc[0][1] = fmaf(xv.x, wv.y, acc[0][1]);
        acc[0][2] = fmaf(xv.x, wv.z, acc[0][2]);
        acc[0][3] = fmaf(xv.x, wv.w, acc[0][3]);
        acc[1][0] = fmaf(xv.y, wv.x, acc[1][0]);
        acc[1][1] = fmaf(xv.y, wv.y, acc[1][1]);
        acc[1][2] = fmaf(xv.y, wv.z, acc[1][2]);
        acc[1][3] = fmaf(xv.y, wv.w, acc[1][3]);
        acc[2][0] = fmaf(xv.z, wv.x, acc[2][0]);
        acc[2][1] = fmaf(xv.z, wv.y, acc[2][1]);
        acc[2][2] = fmaf(xv.z, wv.z, acc[2][2]);
        acc[2][3] = fmaf(xv.z, wv.w, acc[2][3]);
        acc[3][0] = fmaf(xv.w, wv.x, acc[3][0]);
        acc[3][1] = fmaf(xv.w, wv.y, acc[3][1]);
        acc[3][2] = fmaf(xv.w, wv.z, acc[3][2]);
        acc[3][3] = fmaf(xv.w, wv.w, acc[3][3]);
    }

    float a_s[4], a_d[4];
#pragma unroll
    for (int c = 0; c < 4; ++c) { a_s[c] = asrc[4 * tc + c]; a_d[c] = adst[4 * tc + c]; }

#pragma unroll
    for (int r = 0; r < 4; ++r) {
        int n = row0 + 4 * tr + r;
        if (n < NN) {
            int p = 0;
            p = __builtin_amdgcn_cvt_pk_fp8_f32(acc[r][0], acc[r][1], p, false);
            p = __builtin_amdgcn_cvt_pk_fp8_f32(acc[r][2], acc[r][3], p, true);
            h32[n * 16 + tc] = (unsigned)p;
            float ps = acc[r][0] * a_s[0] + acc[r][1] * a_s[1] +
                       acc[r][2] * a_s[2] + acc[r][3] * a_s[3];
            float pd = acc[r][0] * a_d[0] + acc[r][1] * a_d[1] +
                       acc[r][2] * a_d[2] + acc[r][3] * a_d[3];
            ps += __shfl_xor(ps, 1); ps += __shfl_xor(ps, 2);
            pd += __shfl_xor(pd, 1); pd += __shfl_xor(pd, 2);
            if ((tc & 3) == 0) {
                es[n * 4 + (tc >> 2)] = ps;
                ed[n * 4 + (tc >> 2)] = pd;
            }
        }
    }

    // flush pool accumulators
    for (int i = tid; i < GG * 64; i += 256)
        if (sp[i] != 0.f) atomicAdd(&poolout[i], sp[i]);
    if (MODE == 0 && tid < GG && scnt[tid] != 0.f) atomicAdd(&cntout[tid], scnt[tid]);
}

// unpack-and-accumulate 16 fp8 channels (one uint4) into acc16
__device__ __forceinline__ void acc_fp8(float acc16[16], float e, uint4 hv) {
    f32x2 p;
    p = __builtin_amdgcn_cvt_pk_f32_fp8((int)hv.x, false);
    acc16[0] = fmaf(e, p.x, acc16[0]);  acc16[1] = fmaf(e, p.y, acc16[1]);
    p = __builtin_amdgcn_cvt_pk_f32_fp8((int)hv.x, true);
    acc16[2] = fmaf(e, p.x, acc16[2]);  acc16[3] = fmaf(e, p.y, acc16[3]);
    p = __builtin_amdgcn_cvt_pk_f32_fp8((int)hv.y, false);
    acc16[4] = fmaf(e, p.x, acc16[4]);  acc16[5] = fmaf(e, p.y, acc16[5]);
    p = __builtin_amdgcn_cvt_pk_f32_fp8((int)hv.y, true);
    acc16[6] = fmaf(e, p.x, acc16[6]);  acc16[7] = fmaf(e, p.y, acc16[7]);
    p = __builtin_amdgcn_cvt_pk_f32_fp8((int)hv.z, false);
    acc16[8] = fmaf(e, p.x, acc16[8]);  acc16[9] = fmaf(e, p.y, acc16[9]);
    p = __builtin_amdgcn_cvt_pk_f32_fp8((int)hv.z, true);
    acc16[10] = fmaf(e, p.x, acc16[10]); acc16[11] = fmaf(e, p.y, acc16[11]);
    p = __builtin_amdgcn_cvt_pk_f32_fp8((int)hv.w, false);
    acc16[12] = fmaf(e, p.x, acc16[12]); acc16[13] = fmaf(e, p.y, acc16[13]);
    p = __builtin_amdgcn_cvt_pk_f32_fp8((int)hv.w, true);
    acc16[14] = fmaf(e, p.x, acc16[14]); acc16[15] = fmaf(e, p.y, acc16[15]);
}

// ---- fused GAT aggregation + BN statistics; fp8 h, 4 edges/iter x 4 lanes ----
__global__ __launch_bounds__(256) void k_gat_agg(const int* __restrict__ row_start,
                                                 const int* __restrict__ ssrc,
                                                 const float* __restrict__ es,
                                                 const float* __restrict__ ed,
                                                 const unsigned* __restrict__ h32,
                                                 float* __restrict__ agg,
                                                 double* __restrict__ bnrep) {
    __shared__ int   sbuf[16][34];
    __shared__ float exbuf[16][34][4];
    __shared__ float stS[4][64];
    __shared__ float stQ[4][64];

    const int lane16 = threadIdx.x & 15;
    const int grp    = threadIdx.x >> 4;   // 0..15
    const int wid    = threadIdx.x >> 6;   // 0..3
    const int sub    = lane16 >> 2;        // which edge of the quad (0..3)
    const int l4     = lane16 & 3;         // channel-16-block owner == head
    const int n = blockIdx.x * 16 + grp;   // NN % 16 == 0
    const int base = row_start[n];
    const int deg  = row_start[n + 1] - base;
    const float4 edv = *(const float4*)(ed + n * 4);
    const uint4* h128 = (const uint4*)h32; // row = 4 x uint4 (64B)

    float acc16[16] = {};
    float4 denp = make_float4(0.f, 0.f, 0.f, 0.f);

    if (deg <= 32) {
        // ---- alpha phase: 1 edge/lane over up to 2 slots ----
        int s0 = 0, s1 = 0;
        float4 al0 = make_float4(-INFINITY, -INFINITY, -INFINITY, -INFINITY);
        float4 al1 = al0;
        if (lane16 < deg) {
            s0 = ssrc[base + lane16];
            float4 ev = *(const float4*)(es + s0 * 4);
            al0.x = lrelu_att(ev.x + edv.x); al0.y = lrelu_att(ev.y + edv.y);
            al0.z = lrelu_att(ev.z + edv.z); al0.w = lrelu_att(ev.w + edv.w);
        }
        if (lane16 + 16 < deg) {
            s1 = ssrc[base + 16 + lane16];
            float4 ev = *(const float4*)(es + s1 * 4);
            al1.x = lrelu_att(ev.x + edv.x); al1.y = lrelu_att(ev.y + edv.y);
            al1.z = lrelu_att(ev.z + edv.z); al1.w = lrelu_att(ev.w + edv.w);
        }
        float4 mx = make_float4(fmaxf(al0.x, al1.x), fmaxf(al0.y, al1.y),
                                fmaxf(al0.z, al1.z), fmaxf(al0.w, al1.w));
#pragma unroll
        for (int o = 1; o < 16; o <<= 1) {
            mx.x = fmaxf(mx.x, __shfl_xor(mx.x, o));
            mx.y = fmaxf(mx.y, __shfl_xor(mx.y, o));
            mx.z = fmaxf(mx.z, __shfl_xor(mx.z, o));
            mx.w = fmaxf(mx.w, __shfl_xor(mx.w, o));
        }
        float4 ex0 = make_float4(0.f, 0.f, 0.f, 0.f), ex1 = ex0;
        if (lane16 < deg) {
            ex0.x = __expf(al0.x - mx.x); ex0.y = __expf(al0.y - mx.y);
            ex0.z = __expf(al0.z - mx.z); ex0.w = __expf(al0.w - mx.w);
        }
        if (lane16 + 16 < deg) {
            ex1.x = __expf(al1.x - mx.x); ex1.y = __expf(al1.y - mx.y);
            ex1.z = __expf(al1.z - mx.z); ex1.w = __expf(al1.w - mx.w);
        }
        denp.x = ex0.x + ex1.x; denp.y = ex0.y + ex1.y;
        denp.z = ex0.z + ex1.z; denp.w = ex0.w + ex1.w;
        sbuf[grp][lane16] = s0;
        sbuf[grp][lane16 + 16] = s1;
        *(float4*)&exbuf[grp][lane16][0] = ex0;
        *(float4*)&exbuf[grp][lane16 + 16][0] = ex1;
        // wave-coherent LDS within group: no barrier needed
        const int dceil = (deg + 3) & ~3;
#pragma unroll 4
        for (int i = 0; i < dceil; i += 4) {
            int si = sbuf[grp][i + sub];
            float e = exbuf[grp][i + sub][l4];
            uint4 hv = h128[si * 4 + l4];
            acc_fp8(acc16, e, hv);
        }
    } else {
        // ---- slow path: chunked two-pass (deg > 32, rare) ----
        float4 mx = make_float4(-INFINITY, -INFINITY, -INFINITY, -INFINITY);
        for (int c0 = 0; c0 < deg; c0 += 16) {
            if (c0 + lane16 < deg) {
                int s = ssrc[base + c0 + lane16];
                float4 ev = *(const float4*)(es + s * 4);
                mx.x = fmaxf(mx.x, lrelu_att(ev.x + edv.x));
                mx.y = fmaxf(mx.y, lrelu_att(ev.y + edv.y));
                mx.z = fmaxf(mx.z, lrelu_att(ev.z + edv.z));
                mx.w = fmaxf(mx.w, lrelu_att(ev.w + edv.w));
            }
        }
#pragma unroll
        for (int o = 1; o < 16; o <<= 1) {
            mx.x = fmaxf(mx.x, __shfl_xor(mx.x, o));
            mx.y = fmaxf(mx.y, __shfl_xor(mx.y, o));
            mx.z = fmaxf(mx.z, __shfl_xor(mx.z, o));
            mx.w = fmaxf(mx.w, __shfl_xor(mx.w, o));
        }
        for (int c0 = 0; c0 < deg; c0 += 16) {
            int cn = min(16, deg - c0);
            float4 ex = make_float4(0.f, 0.f, 0.f, 0.f);
            int s = 0;
            if (lane16 < cn) {
                s = ssrc[base + c0 + lane16];
                float4 ev = *(const float4*)(es + s * 4);
                ex.x = __expf(lrelu_att(ev.x + edv.x) - mx.x);
                ex.y = __expf(lrelu_att(ev.y + edv.y) - mx.y);
                ex.z = __expf(lrelu_att(ev.z + edv.z) - mx.z);
                ex.w = __expf(lrelu_att(ev.w + edv.w) - mx.w);
            }
            denp.x += ex.x; denp.y += ex.y; denp.z += ex.z; denp.w += ex.w;
            sbuf[grp][lane16] = s;
            *(float4*)&exbuf[grp][lane16][0] = ex;
            const int pc = (cn + 3) & ~3;
            for (int i = 0; i < pc; i += 4) {
                int si = sbuf[grp][i + sub];
                float e = exbuf[grp][i + sub][l4];
                uint4 hv = h128[si * 4 + l4];
                acc_fp8(acc16, e, hv);
            }
        }
    }

    // ---- join: fold the edge quad (xor 4, 8 within the 16-lane group) ----
#pragma unroll
    for (int q = 0; q < 16; ++q) {
        acc16[q] += __shfl_xor(acc16[q], 4);
        acc16[q] += __shfl_xor(acc16[q], 8);
    }
#pragma unroll
    for (int o = 1; o < 16; o <<= 1) {
        denp.x += __shfl_xor(denp.x, o);
        denp.y += __shfl_xor(denp.y, o);
        denp.z += __shfl_xor(denp.z, o);
        denp.w += __shfl_xor(denp.w, o);
    }
    float dh = l4 == 0 ? denp.x : l4 == 1 ? denp.y : l4 == 2 ? denp.z : denp.w;
    float inv = 1.f / (dh + 1e-16f);
    float o16[16];
#pragma unroll
    for (int q = 0; q < 16; ++q) o16[q] = acc16[q] * inv;

    if (lane16 < 4) {
#pragma unroll
        for (int q4 = 0; q4 < 4; ++q4)
            *(float4*)(agg + n * 64 + lane16 * 16 + q4 * 4) =
                make_float4(o16[q4 * 4], o16[q4 * 4 + 1], o16[q4 * 4 + 2], o16[q4 * 4 + 3]);
    }

    // ---- BN stats: shuffle-reduce across the wave's 4 nodes ----
    float sv[16], qv[16];
#pragma unroll
    for (int q = 0; q < 16; ++q) {
        float v = (lane16 < 4) ? o16[q] : 0.f;
        sv[q] = v; qv[q] = v * v;
    }
#pragma unroll
    for (int q = 0; q < 16; ++q) {
        sv[q] += __shfl_xor(sv[q], 16); sv[q] += __shfl_xor(sv[q], 32);
        qv[q] += __shfl_xor(qv[q], 16); qv[q] += __shfl_xor(qv[q], 32);
    }
    if ((threadIdx.x & 63) < 4) {
#pragma unroll
        for (int q4 = 0; q4 < 4; ++q4) {
            *(float4*)&stS[wid][l4 * 16 + q4 * 4] =
                make_float4(sv[q4 * 4], sv[q4 * 4 + 1], sv[q4 * 4 + 2], sv[q4 * 4 + 3]);
            *(float4*)&stQ[wid][l4 * 16 + q4 * 4] =
                make_float4(qv[q4 * 4], qv[q4 * 4 + 1], qv[q4 * 4 + 2], qv[q4 * 4 + 3]);
        }
    }
    __syncthreads();
    if (threadIdx.x < 64) {
        int j = threadIdx.x;
        float ssum = stS[0][j] + stS[1][j] + stS[2][j] + stS[3][j];
        float qsum = stQ[0][j] + stQ[1][j] + stQ[2][j] + stQ[3][j];
        double* rep = bnrep + (size_t)(blockIdx.x & (NREP - 1)) * 128;
        atomicAdd(&rep[j], (double)ssum);
        atomicAdd(&rep[64 + j], (double)qsum);
    }
}

// ---- BN finalize: 1 block, 64 threads -> scshf ----
__global__ void k_bn_final(const double* __restrict__ bnrep,
                           const float* __restrict__ gamma,
                           const float* __restrict__ beta,
                           float* __restrict__ scshf) {
    int j = threadIdx.x;
    if (j < 64) {
        double s1 = 0.0, s2 = 0.0;
        for (int rp = 0; rp < NREP; ++rp) {
            s1 += bnrep[(size_t)rp * 128 + j];
            s2 += bnrep[(size_t)rp * 128 + 64 + j];
        }
        double mean = s1 / (double)NN;
        double var = s2 / (double)NN - mean * mean;
        float sc = (float)(1.0 / sqrt(var + (double)EPS)) * gamma[j];
        scshf[j] = sc;
        scshf[64 + j] = beta[j] - (float)mean * sc;
    }
}

// ---- final layer pool ----
constexpr int NA_BLOCKS = 512;
constexpr int NA_NODES = (NN + NA_BLOCKS - 1) / NA_BLOCKS;   // 196
__global__ __launch_bounds__(256) void k_pool_final(const float* __restrict__ agg,
                                                    const float* __restrict__ scshf,
                                                    const int* __restrict__ batch,
                                                    const float* __restrict__ cnt,
                                                    float* __restrict__ pool) {
    __shared__ float sp[GG * 64];
    for (int i = threadIdx.x; i < GG * 64; i += 256) sp[i] = 0.f;
    __syncthreads();
    const int j = threadIdx.x & 63, r = threadIdx.x >> 6;
    const float sc = scshf[j], shf = scshf[64 + j];
    const int n0 = blockIdx.x * NA_NODES;
    const int n1 = min(n0 + NA_NODES, NN);
    float racc = 0.f;
    int curg = -1;
    float rinv = 0.f;
    for (int n = n0 + r; n < n1; n += 4) {
        int g = batch[n];
        if (g != curg) {
            if (curg >= 0) atomicAdd(&sp[curg * 64 + j], racc);
            curg = g; racc = 0.f;
            rinv = rsqrtf(cnt[g]);
        }
        float v = (agg[n * 64 + j] * sc + shf) * rinv;
        racc += lrelu_act(v);
    }
    if (curg >= 0) atomicAdd(&sp[curg * 64 + j], racc);
    __syncthreads();
    for (int i = threadIdx.x; i < GG * 64; i += 256)
        if (sp[i] != 0.f) atomicAdd(&pool[i], sp[i]);
}

// ---- readout head ----
__global__ void k_head(const float* __restrict__ pools,
                       const float* __restrict__ cnt,
                       const float* __restrict__ Wr,
                       const float* __restrict__ br,
                       float* __restrict__ out) {
    __shared__ float risk[GG * NCLS];
    int t = threadIdx.x;
    if (t < GG * NCLS) {
        int g = t / NCLS, c = t % NCLS;
        float acc = br[c];
        float icnt = 1.f / cnt[g];
        for (int k = 0; k < (LL + 1) * DIM; ++k) {
            int l = k >> 6, j = k & 63;
            float xc = pools[(l * GG + g) * 64 + j] * icnt;
            acc += xc * Wr[k * NCLS + c];
        }
        risk[t] = acc;
        out[t] = acc;
    }
    __syncthreads();
    if (t < GG) {
        float r0 = risk[t * 2], r1 = risk[t * 2 + 1];
        float m = fmaxf(r0, r1);
        float e0 = expf(r0 - m), e1 = expf(r1 - m);
        float s = e0 + e1;
        out[GG * NCLS + t * 2] = e0 / s;
        out[GG * NCLS + t * 2 + 1] = e1 / s;
        out[2 * GG * NCLS + t] = (r1 > r0) ? 1.f : 0.f;
    }
}

extern "C" void kernel_launch(void* const* d_in, const int* in_sizes, int n_in,
                              void* d_out, int out_size, void* d_ws, size_t ws_size,
                              hipStream_t stream) {
    const float* x     = (const float*)d_in[0];
    const int*   ei    = (const int*)d_in[1];
    const int*   batch = (const int*)d_in[2];
    const float* W     = (const float*)d_in[4];
    const float* asrc  = (const float*)d_in[5];
    const float* adst  = (const float*)d_in[6];
    const float* gamma = (const float*)d_in[8];
    const float* beta  = (const float*)d_in[9];
    const float* Wr    = (const float*)d_in[10];
    const float* br    = (const float*)d_in[11];
    float* out = (float*)d_out;

    char* ws = (char*)d_ws;
    size_t off = 0;
    auto alloc = [&](size_t bytes) {
        void* p = ws + off;
        off += (bytes + 255) & ~(size_t)255;
        return p;
    };
    float*    xcur      = (float*)alloc((size_t)NN * 64 * 4);
    unsigned* h32       = (unsigned*)alloc((size_t)NN * 64);       // fp8, 16 uints/row
    float*    agg       = (float*)alloc((size_t)NN * 64 * 4);
    float*    es        = (float*)alloc((size_t)NN * 4 * 4);
    float*    ed        = (float*)alloc((size_t)NN * 4 * 4);
    int*      row_start = (int*)alloc((size_t)(NN + 1) * 4);
    int*      ssrc      = (int*)alloc((size_t)EE * 4);
    double*   bnrep     = (double*)alloc((size_t)NREP * 128 * 8);
    float*    scshf     = (float*)alloc(128 * 4);
    float*    pools     = (float*)alloc((size_t)(LL + 1) * GG * 64 * 4);  // 16384 B
    float*    cnt       = (float*)alloc((size_t)GG * 4);                  // adjacent
    (void)ws_size; (void)in_sizes; (void)n_in; (void)out_size;

    // CSR-build scratch aliases agg (dead until k_gat_agg overwrites it)
    int* deg    = (int*)agg;
    int* cursor = (int*)agg + NN;
    int* bsum   = (int*)agg + 2 * NN;

    // pools (16384 B) and cnt (64 B) are contiguous: one memset
    hipMemsetAsync(pools, 0, (size_t)(LL + 1) * GG * 64 * 4 + GG * 4, stream);
    hipMemsetAsync(deg, 0, (size_t)NN * 4, stream);

    // ---- build CSR (once; reused by all 3 layers) ----
    k_hist<<<(EE / 4 + 255) / 256, 256, 0, stream>>>(ei, deg);
    k_scan1<<<NSCAN, 256, 0, stream>>>(deg, row_start, bsum);
    k_scan23<<<(NN + 255) / 256, 256, 0, stream>>>(row_start, bsum, cursor);
    k_fill<<<8 * FILL_NBLK, 256, 0, stream>>>(ei, cursor, ssrc);

    const int GEMM_GRID = (NN + 63) / 64;

    // ---- layer 0 ----
    k_gemm_t<0><<<GEMM_GRID, 256, 0, stream>>>(x, nullptr, nullptr, batch, nullptr,
                                               W, asrc, adst, nullptr,
                                               h32, es, ed, bnrep, pools, cnt);
    k_gat_agg<<<NN / 16, 256, 0, stream>>>(row_start, ssrc, es, ed, h32, agg, bnrep);
    k_bn_final<<<1, 64, 0, stream>>>(bnrep, gamma, beta, scshf);

    // ---- layer 1 ----
    k_gemm_t<1><<<GEMM_GRID, 256, 0, stream>>>(x, agg, scshf, batch, cnt,
                                               W + DIM * DIM, asrc + HH * CC, adst + HH * CC,
                                               xcur, h32, es, ed, bnrep,
                                               pools + GG * 64, nullptr);
    k_gat_agg<<<NN / 16, 256, 0, stream>>>(row_start, ssrc, es, ed, h32, agg, bnrep);
    k_bn_final<<<1, 64, 0, stream>>>(bnrep, gamma + DIM, beta + DIM, scshf);

    // ---- layer 2 ----
    k_gemm_t<1><<<GEMM_GRID, 256, 0, stream>>>(xcur, agg, scshf, batch, cnt,
                                               W + 2 * DIM * DIM, asrc + 2 * HH * CC,
                                               adst + 2 * HH * CC,
                                               xcur, h32, es, ed, bnrep,
                                               pools + 2 * GG * 64, nullptr);
    k_gat_agg<<<NN / 16, 256, 0, stream>>>(row_start, ssrc, es, ed, h32, agg, bnrep);
    k_bn_final<<<1, 64, 0, stream>>>(bnrep, gamma + 2 * DIM, beta + 2 * DIM, scshf);

    // ---- final pool of layer-2 activations ----
    k_pool_final<<<NA_BLOCKS, 256, 0, stream>>>(agg, scshf, batch, cnt,
                                                pools + 3 * GG * 64);

    k_head<<<1, 64, 0, stream>>>(pools, cnt, Wr, br, out);
}

// Round 12
// 562.640 us; speedup vs baseline: 1.0854x; 1.0854x over previous
//
#include <hip/hip_runtime.h>

// Problem constants (fixed by the reference)
constexpr int NN   = 100000;   // nodes
constexpr int EE   = 1600000;  // edges
constexpr int DIM  = 64;
constexpr int HH   = 4;        // heads
constexpr int CC   = 16;       // channels / head
constexpr int LL   = 3;        // layers
constexpr int GG   = 16;       // graphs
constexpr int NCLS = 2;
constexpr float SLOPE_ATT = 0.2f;
constexpr float SLOPE_ACT = 0.01f;
constexpr float EPS = 1e-5f;

constexpr int SCAN_CHUNK = 1024;
constexpr int NSCAN = (NN + SCAN_CHUNK - 1) / SCAN_CHUNK;   // 98
constexpr int NREP = 64;                                    // BN stat replicas

typedef int vint4 __attribute__((ext_vector_type(4)));

__device__ __forceinline__ float lrelu_att(float v) { return v > 0.f ? v : SLOPE_ATT * v; }
__device__ __forceinline__ float lrelu_act(float v) { return v > 0.f ? v : SLOPE_ACT * v; }

// bf16 helpers
__device__ __forceinline__ unsigned short f2bf(float f) {
    unsigned u = __float_as_uint(f);
    unsigned r = u + 0x7FFFu + ((u >> 16) & 1u);
    return (unsigned short)(r >> 16);
}
__device__ __forceinline__ float bflo(unsigned u) { return __uint_as_float(u << 16); }
__device__ __forceinline__ float bfhi(unsigned u) { return __uint_as_float(u & 0xFFFF0000u); }

// ---- CSR build: histogram of dst + per-edge rank (atomic return value) ----
__global__ __launch_bounds__(256) void k_hist(const int* __restrict__ ei,
                                              int* __restrict__ deg,
                                              int* __restrict__ rank) {
    int i = blockIdx.x * 256 + threadIdx.x;
    if (i < EE / 4) {
        vint4 d = __builtin_nontemporal_load(&((const vint4*)(ei + EE))[i]);
        vint4 r;
        r.x = atomicAdd(&deg[d.x], 1);
        r.y = atomicAdd(&deg[d.y], 1);
        r.z = atomicAdd(&deg[d.z], 1);
        r.w = atomicAdd(&deg[d.w], 1);
        __builtin_nontemporal_store(r, &((vint4*)rank)[i]);
    }
}

// ---- scan step 1: per-chunk exclusive scan + chunk totals ----
__global__ __launch_bounds__(256) void k_scan1(const int* __restrict__ deg,
                                               int* __restrict__ excl,
                                               int* __restrict__ bsum) {
    __shared__ int sh[256];
    const int b = blockIdx.x, t = threadIdx.x;
    const int i0 = b * SCAN_CHUNK + t * 4;
    int v[4];
#pragma unroll
    for (int i = 0; i < 4; ++i) v[i] = (i0 + i < NN) ? deg[i0 + i] : 0;
    int tsum = v[0] + v[1] + v[2] + v[3];
    sh[t] = tsum;
    __syncthreads();
    for (int o = 1; o < 256; o <<= 1) {
        int x = (t >= o) ? sh[t - o] : 0;
        __syncthreads();
        sh[t] += x;
        __syncthreads();
    }
    if (t == 255) bsum[b] = sh[255];
    int run = sh[t] - tsum;
#pragma unroll
    for (int i = 0; i < 4; ++i) {
        if (i0 + i < NN) excl[i0 + i] = run;
        run += v[i];
    }
}

// ---- scan steps 2+3 merged: per-block prefix of chunk totals + apply ----
__global__ __launch_bounds__(256) void k_scan23(int* __restrict__ row_start,
                                                const int* __restrict__ bsum) {
    __shared__ int sh[128];
    __shared__ int prefix;
    const int t = threadIdx.x;
    if (t < NSCAN) sh[t] = bsum[t];
    __syncthreads();
    if (t == 0) {
        int ci = blockIdx.x >> 2;           // 256 nodes/block, 1024/chunk
        int p = 0;
        for (int k = 0; k < ci; ++k) p += sh[k];
        prefix = p;
    }
    __syncthreads();
    int i = blockIdx.x * 256 + t;
    if (i < NN) row_start[i] = row_start[i] + prefix;
    if (i == 0) row_start[NN] = EE;
}

// ---- CSR fill: XCD dst-range partitioned, rank-based (no atomics) ----
constexpr int FILL_NBLK = 256;
constexpr int DRANGE = (NN + 7) / 8;
__global__ __launch_bounds__(256) void k_fill(const int* __restrict__ ei,
                                              const int* __restrict__ rank,
                                              const int* __restrict__ row_start,
                                              int* __restrict__ ssrc) {
    const int g = blockIdx.x & 7;
    const int blk = blockIdx.x >> 3;
    const int dlo = g * DRANGE, dhi = min(dlo + DRANGE, NN);
    const int stride = FILL_NBLK * 256;
    for (int e = blk * 256 + threadIdx.x; e < EE; e += stride) {
        int d = __builtin_nontemporal_load(&ei[EE + e]);
        if (d >= dlo && d < dhi) {
            int s = __builtin_nontemporal_load(&ei[e]);
            int r = __builtin_nontemporal_load(&rank[e]);
            ssrc[row_start[d] + r] = s;
        }
    }
}

// ---- GEMM, templated:
// MODE 0: x-input layer; also accumulates pools[0] + cnt.
// MODE 1: fused layer tail (BN+GSN+act+pool+residual), writes xcur, then gemm.
// MODE 2: MODE 1 without the xcur store (last layer: nothing reads it).
template<int MODE>
__global__ __launch_bounds__(256) void k_gemm_t(const float* __restrict__ xbase,
                                                const float* __restrict__ aggin,
                                                const float* __restrict__ scshf,
                                                const int* __restrict__ batch,
                                                const float* __restrict__ cntin,
                                                const float* __restrict__ Wl,
                                                const float* __restrict__ asrc,
                                                const float* __restrict__ adst,
                                                float* __restrict__ xcur_out,
                                                unsigned short* __restrict__ h,
                                                float* __restrict__ es,
                                                float* __restrict__ ed,
                                                double* __restrict__ bnrep,
                                                float* __restrict__ poolout,
                                                float* __restrict__ cntout) {
    if (blockIdx.x < NREP && threadIdx.x < 128)
        bnrep[(size_t)blockIdx.x * 128 + threadIdx.x] = 0.0;
    __shared__ float Ws[DIM][DIM];
    __shared__ float xsT[DIM][DIM];
    __shared__ float sp[GG * 64];
    __shared__ float scnt[GG];
    const int tid = threadIdx.x;
    const int row0 = blockIdx.x * 64;

    for (int i = tid; i < GG * 64; i += 256) sp[i] = 0.f;
    if (MODE == 0 && tid < GG) scnt[tid] = 0.f;
    __syncthreads();

    const float4* W4 = (const float4*)Wl;
#pragma unroll
    for (int i = 0; i < 4; ++i) ((float4*)Ws)[tid + 256 * i] = W4[tid + 256 * i];

    const int c4_ = tid & 15;
    float4 scv, shfv;
    if (MODE >= 1) {
        scv  = ((const float4*)scshf)[c4_];
        shfv = ((const float4*)scshf)[16 + c4_];
    }

#pragma unroll
    for (int i = 0; i < 4; ++i) {
        int idx4 = tid + 256 * i;
        int r = idx4 >> 4, c4 = idx4 & 15;
        int grow = row0 + r;
        float4 v4 = make_float4(0.f, 0.f, 0.f, 0.f);
        if (grow < NN) {
            if (MODE == 0) {
                v4 = ((const float4*)xbase)[grow * 16 + c4];
                int g = batch[grow];
                atomicAdd(&sp[g * 64 + c4 * 4 + 0], v4.x);
                atomicAdd(&sp[g * 64 + c4 * 4 + 1], v4.y);
                atomicAdd(&sp[g * 64 + c4 * 4 + 2], v4.z);
                atomicAdd(&sp[g * 64 + c4 * 4 + 3], v4.w);
                if (c4 == 0) atomicAdd(&scnt[g], 1.f);
            } else {
                float4 a4 = ((const float4*)aggin)[grow * 16 + c4];
                float4 xb = ((const float4*)xbase)[grow * 16 + c4];
                int g = batch[grow];
                float rinv = rsqrtf(cntin[g]);
                float vx = lrelu_act((a4.x * scv.x + shfv.x) * rinv);
                float vy = lrelu_act((a4.y * scv.y + shfv.y) * rinv);
                float vz = lrelu_act((a4.z * scv.z + shfv.z) * rinv);
                float vw = lrelu_act((a4.w * scv.w + shfv.w) * rinv);
                atomicAdd(&sp[g * 64 + c4 * 4 + 0], vx);
                atomicAdd(&sp[g * 64 + c4 * 4 + 1], vy);
                atomicAdd(&sp[g * 64 + c4 * 4 + 2], vz);
                atomicAdd(&sp[g * 64 + c4 * 4 + 3], vw);
                v4 = make_float4(xb.x + vx, xb.y + vy, xb.z + vz, xb.w + vw);
                if (MODE == 1) ((float4*)xcur_out)[grow * 16 + c4] = v4;
            }
        }
        int col = (((r >> 2) ^ c4) << 2) | (r & 3);
        xsT[c4 * 4 + 0][col] = v4.x;
        xsT[c4 * 4 + 1][col] = v4.y;
        xsT[c4 * 4 + 2][col] = v4.z;
        xsT[c4 * 4 + 3][col] = v4.w;
    }
    __syncthreads();

    const int tc = tid & 15, tr = tid >> 4;
    float acc[4][4] = {};
#pragma unroll 8
    for (int k = 0; k < DIM; ++k) {
        int kc = (k >> 2) & 15;
        float4 wv = *(const float4*)(&Ws[k][tc * 4]);
        float4 xv = *(const float4*)(&xsT[k][(tr ^ kc) * 4]);
        acc[0][0] = fmaf(xv.x, wv.x, acc[0][0]);
        acc[0][1] = fmaf(xv.x, wv.y, acc[0][1]);
        acc[0][2] = fmaf(xv.x, wv.z, acc[0][2]);
        acc[0][3] = fmaf(xv.x, wv.w, acc[0][3]);
        acc[1][0] = fmaf(xv.y, wv.x, acc[1][0]);
        acc[1][1] = fmaf(xv.y, wv.y, acc[1][1]);
        acc[1][2] = fmaf(xv.y, wv.z, acc[1][2]);
        acc[1][3] = fmaf(xv.y, wv.w, acc[1][3]);
        acc[2][0] = fmaf(xv.z, wv.x, acc[2][0]);
        acc[2][1] = fmaf(xv.z, wv.y, acc[2][1]);
        acc[2][2] = fmaf(xv.z, wv.z, acc[2][2]);
        acc[2][3] = fmaf(xv.z, wv.w, acc[2][3]);
        acc[3][0] = fmaf(xv.w, wv.x, acc[3][0]);
        acc[3][1] = fmaf(xv.w, wv.y, acc[3][1]);
        acc[3][2] = fmaf(xv.w, wv.z, acc[3][2]);
        acc[3][3] = fmaf(xv.w, wv.w, acc[3][3]);
    }

    float a_s[4], a_d[4];
#pragma unroll
    for (int c = 0; c < 4; ++c) { a_s[c] = asrc[4 * tc + c]; a_d[c] = adst[4 * tc + c]; }

#pragma unroll
    for (int r = 0; r < 4; ++r) {
        int n = row0 + 4 * tr + r;
        if (n < NN) {
            ushort4 hb;
            hb.x = f2bf(acc[r][0]); hb.y = f2bf(acc[r][1]);
            hb.z = f2bf(acc[r][2]); hb.w = f2bf(acc[r][3]);
            *(ushort4*)(h + n * 64 + 4 * tc) = hb;
            float ps = acc[r][0] * a_s[0] + acc[r][1] * a_s[1] +
                       acc[r][2] * a_s[2] + acc[r][3] * a_s[3];
            float pd = acc[r][0] * a_d[0] + acc[r][1] * a_d[1] +
                       acc[r][2] * a_d[2] + acc[r][3] * a_d[3];
            ps += __shfl_xor(ps, 1); ps += __shfl_xor(ps, 2);
            pd += __shfl_xor(pd, 1); pd += __shfl_xor(pd, 2);
            if ((tc & 3) == 0) {
                es[n * 4 + (tc >> 2)] = ps;
                ed[n * 4 + (tc >> 2)] = pd;
            }
        }
    }

    // flush pool accumulators
    for (int i = tid; i < GG * 64; i += 256)
        if (sp[i] != 0.f) atomicAdd(&poolout[i], sp[i]);
    if (MODE == 0 && tid < GG && scnt[tid] != 0.f) atomicAdd(&cntout[tid], scnt[tid]);
}

// ---- fused GAT aggregation + BN statistics (bf16 h; round-10 form) ----
__global__ __launch_bounds__(256) void k_gat_agg(const int* __restrict__ row_start,
                                                 const int* __restrict__ ssrc,
                                                 const float* __restrict__ es,
                                                 const float* __restrict__ ed,
                                                 const unsigned short* __restrict__ h,
                                                 float* __restrict__ agg,
                                                 double* __restrict__ bnrep) {
    __shared__ int   sbuf[16][34];
    __shared__ float exbuf[16][34][4];
    __shared__ float stS[4][64];
    __shared__ float stQ[4][64];

    const int lane16 = threadIdx.x & 15;
    const int grp    = threadIdx.x >> 4;   // 0..15
    const int wid    = threadIdx.x >> 6;   // 0..3
    const int sub    = lane16 >> 3;        // which edge of the pair
    const int l8     = lane16 & 7;         // channel-octet owner
    const int hq8    = l8 >> 1;            // head of channels 8*l8..8*l8+7
    const int n = blockIdx.x * 16 + grp;   // NN % 16 == 0
    const int base = row_start[n];
    const int deg  = row_start[n + 1] - base;
    const float4 edv = *(const float4*)(ed + n * 4);
    const uint4* h16 = (const uint4*)h;

    float acc8[8] = {};
    float4 denp = make_float4(0.f, 0.f, 0.f, 0.f);

    if (deg <= 32) {
        int s0 = 0, s1 = 0;
        float4 al0 = make_float4(-INFINITY, -INFINITY, -INFINITY, -INFINITY);
        float4 al1 = al0;
        if (lane16 < deg) {
            s0 = ssrc[base + lane16];
            float4 ev = *(const float4*)(es + s0 * 4);
            al0.x = lrelu_att(ev.x + edv.x); al0.y = lrelu_att(ev.y + edv.y);
            al0.z = lrelu_att(ev.z + edv.z); al0.w = lrelu_att(ev.w + edv.w);
        }
        if (lane16 + 16 < deg) {
            s1 = ssrc[base + 16 + lane16];
            float4 ev = *(const float4*)(es + s1 * 4);
            al1.x = lrelu_att(ev.x + edv.x); al1.y = lrelu_att(ev.y + edv.y);
            al1.z = lrelu_att(ev.z + edv.z); al1.w = lrelu_att(ev.w + edv.w);
        }
        float4 mx = make_float4(fmaxf(al0.x, al1.x), fmaxf(al0.y, al1.y),
                                fmaxf(al0.z, al1.z), fmaxf(al0.w, al1.w));
#pragma unroll
        for (int o = 1; o < 16; o <<= 1) {
            mx.x = fmaxf(mx.x, __shfl_xor(mx.x, o));
            mx.y = fmaxf(mx.y, __shfl_xor(mx.y, o));
            mx.z = fmaxf(mx.z, __shfl_xor(mx.z, o));
            mx.w = fmaxf(mx.w, __shfl_xor(mx.w, o));
        }
        float4 ex0 = make_float4(0.f, 0.f, 0.f, 0.f), ex1 = ex0;
        if (lane16 < deg) {
            ex0.x = __expf(al0.x - mx.x); ex0.y = __expf(al0.y - mx.y);
            ex0.z = __expf(al0.z - mx.z); ex0.w = __expf(al0.w - mx.w);
        }
        if (lane16 + 16 < deg) {
            ex1.x = __expf(al1.x - mx.x); ex1.y = __expf(al1.y - mx.y);
            ex1.z = __expf(al1.z - mx.z); ex1.w = __expf(al1.w - mx.w);
        }
        denp.x = ex0.x + ex1.x; denp.y = ex0.y + ex1.y;
        denp.z = ex0.z + ex1.z; denp.w = ex0.w + ex1.w;
        sbuf[grp][lane16] = s0;
        sbuf[grp][lane16 + 16] = s1;
        *(float4*)&exbuf[grp][lane16][0] = ex0;
        *(float4*)&exbuf[grp][lane16 + 16][0] = ex1;
        const int dceil = (deg + 1) & ~1;
#pragma unroll 4
        for (int i = 0; i < dceil; i += 2) {
            int si = sbuf[grp][i + sub];
            float e = exbuf[grp][i + sub][hq8];
            uint4 hv = h16[si * 8 + l8];
            acc8[0] = fmaf(e, bflo(hv.x), acc8[0]);
            acc8[1] = fmaf(e, bfhi(hv.x), acc8[1]);
            acc8[2] = fmaf(e, bflo(hv.y), acc8[2]);
            acc8[3] = fmaf(e, bfhi(hv.y), acc8[3]);
            acc8[4] = fmaf(e, bflo(hv.z), acc8[4]);
            acc8[5] = fmaf(e, bfhi(hv.z), acc8[5]);
            acc8[6] = fmaf(e, bflo(hv.w), acc8[6]);
            acc8[7] = fmaf(e, bfhi(hv.w), acc8[7]);
        }
    } else {
        float4 mx = make_float4(-INFINITY, -INFINITY, -INFINITY, -INFINITY);
        for (int c0 = 0; c0 < deg; c0 += 16) {
            if (c0 + lane16 < deg) {
                int s = ssrc[base + c0 + lane16];
                float4 ev = *(const float4*)(es + s * 4);
                mx.x = fmaxf(mx.x, lrelu_att(ev.x + edv.x));
                mx.y = fmaxf(mx.y, lrelu_att(ev.y + edv.y));
                mx.z = fmaxf(mx.z, lrelu_att(ev.z + edv.z));
                mx.w = fmaxf(mx.w, lrelu_att(ev.w + edv.w));
            }
        }
#pragma unroll
        for (int o = 1; o < 16; o <<= 1) {
            mx.x = fmaxf(mx.x, __shfl_xor(mx.x, o));
            mx.y = fmaxf(mx.y, __shfl_xor(mx.y, o));
            mx.z = fmaxf(mx.z, __shfl_xor(mx.z, o));
            mx.w = fmaxf(mx.w, __shfl_xor(mx.w, o));
        }
        for (int c0 = 0; c0 < deg; c0 += 16) {
            int cn = min(16, deg - c0);
            float4 ex = make_float4(0.f, 0.f, 0.f, 0.f);
            int s = 0;
            if (lane16 < cn) {
                s = ssrc[base + c0 + lane16];
                float4 ev = *(const float4*)(es + s * 4);
                ex.x = __expf(lrelu_att(ev.x + edv.x) - mx.x);
                ex.y = __expf(lrelu_att(ev.y + edv.y) - mx.y);
                ex.z = __expf(lrelu_att(ev.z + edv.z) - mx.z);
                ex.w = __expf(lrelu_att(ev.w + edv.w) - mx.w);
            }
            denp.x += ex.x; denp.y += ex.y; denp.z += ex.z; denp.w += ex.w;
            sbuf[grp][lane16] = s;
            *(float4*)&exbuf[grp][lane16][0] = ex;
            const int pc = (cn + 1) & ~1;
            for (int i = 0; i < pc; i += 2) {
                int si = sbuf[grp][i + sub];
                float e = exbuf[grp][i + sub][hq8];
                uint4 hv = h16[si * 8 + l8];
                acc8[0] = fmaf(e, bflo(hv.x), acc8[0]);
                acc8[1] = fmaf(e, bfhi(hv.x), acc8[1]);
                acc8[2] = fmaf(e, bflo(hv.y), acc8[2]);
                acc8[3] = fmaf(e, bfhi(hv.y), acc8[3]);
                acc8[4] = fmaf(e, bflo(hv.z), acc8[4]);
                acc8[5] = fmaf(e, bfhi(hv.z), acc8[5]);
                acc8[6] = fmaf(e, bflo(hv.w), acc8[6]);
                acc8[7] = fmaf(e, bfhi(hv.w), acc8[7]);
            }
        }
    }

#pragma unroll
    for (int q = 0; q < 8; ++q) acc8[q] += __shfl_xor(acc8[q], 8);
#pragma unroll
    for (int o = 1; o < 16; o <<= 1) {
        denp.x += __shfl_xor(denp.x, o);
        denp.y += __shfl_xor(denp.y, o);
        denp.z += __shfl_xor(denp.z, o);
        denp.w += __shfl_xor(denp.w, o);
    }
    float dh = hq8 == 0 ? denp.x : hq8 == 1 ? denp.y : hq8 == 2 ? denp.z : denp.w;
    float inv = 1.f / (dh + 1e-16f);
    float o8[8];
#pragma unroll
    for (int q = 0; q < 8; ++q) o8[q] = acc8[q] * inv;

    if (sub == 0) {
        *(float4*)(agg + n * 64 + l8 * 8)     = make_float4(o8[0], o8[1], o8[2], o8[3]);
        *(float4*)(agg + n * 64 + l8 * 8 + 4) = make_float4(o8[4], o8[5], o8[6], o8[7]);
    }

    // BN stats: shuffle-reduce across the wave's 4 nodes
    float sv[8], qv[8];
#pragma unroll
    for (int q = 0; q < 8; ++q) {
        float v = (sub == 0) ? o8[q] : 0.f;
        sv[q] = v; qv[q] = v * v;
    }
#pragma unroll
    for (int q = 0; q < 8; ++q) {
        sv[q] += __shfl_xor(sv[q], 16); sv[q] += __shfl_xor(sv[q], 32);
        qv[q] += __shfl_xor(qv[q], 16); qv[q] += __shfl_xor(qv[q], 32);
    }
    if ((threadIdx.x & 63) < 8) {
        *(float4*)&stS[wid][l8 * 8]     = make_float4(sv[0], sv[1], sv[2], sv[3]);
        *(float4*)&stS[wid][l8 * 8 + 4] = make_float4(sv[4], sv[5], sv[6], sv[7]);
        *(float4*)&stQ[wid][l8 * 8]     = make_float4(qv[0], qv[1], qv[2], qv[3]);
        *(float4*)&stQ[wid][l8 * 8 + 4] = make_float4(qv[4], qv[5], qv[6], qv[7]);
    }
    __syncthreads();
    if (threadIdx.x < 64) {
        int j = threadIdx.x;
        float ssum = stS[0][j] + stS[1][j] + stS[2][j] + stS[3][j];
        float qsum = stQ[0][j] + stQ[1][j] + stQ[2][j] + stQ[3][j];
        double* rep = bnrep + (size_t)(blockIdx.x & (NREP - 1)) * 128;
        atomicAdd(&rep[j], (double)ssum);
        atomicAdd(&rep[64 + j], (double)qsum);
    }
}

// ---- BN finalize: 1 block, 64 threads -> scshf ----
__global__ void k_bn_final(const double* __restrict__ bnrep,
                           const float* __restrict__ gamma,
                           const float* __restrict__ beta,
                           float* __restrict__ scshf) {
    int j = threadIdx.x;
    if (j < 64) {
        double s1 = 0.0, s2 = 0.0;
        for (int rp = 0; rp < NREP; ++rp) {
            s1 += bnrep[(size_t)rp * 128 + j];
            s2 += bnrep[(size_t)rp * 128 + 64 + j];
        }
        double mean = s1 / (double)NN;
        double var = s2 / (double)NN - mean * mean;
        float sc = (float)(1.0 / sqrt(var + (double)EPS)) * gamma[j];
        scshf[j] = sc;
        scshf[64 + j] = beta[j] - (float)mean * sc;
    }
}

// ---- final layer pool ----
constexpr int NA_BLOCKS = 512;
constexpr int NA_NODES = (NN + NA_BLOCKS - 1) / NA_BLOCKS;   // 196
__global__ __launch_bounds__(256) void k_pool_final(const float* __restrict__ agg,
                                                    const float* __restrict__ scshf,
                                                    const int* __restrict__ batch,
                                                    const float* __restrict__ cnt,
                                                    float* __restrict__ pool) {
    __shared__ float sp[GG * 64];
    for (int i = threadIdx.x; i < GG * 64; i += 256) sp[i] = 0.f;
    __syncthreads();
    const int j = threadIdx.x & 63, r = threadIdx.x >> 6;
    const float sc = scshf[j], shf = scshf[64 + j];
    const int n0 = blockIdx.x * NA_NODES;
    const int n1 = min(n0 + NA_NODES, NN);
    float racc = 0.f;
    int curg = -1;
    float rinv = 0.f;
    for (int n = n0 + r; n < n1; n += 4) {
        int g = batch[n];
        if (g != curg) {
            if (curg >= 0) atomicAdd(&sp[curg * 64 + j], racc);
            curg = g; racc = 0.f;
            rinv = rsqrtf(cnt[g]);
        }
        float v = (agg[n * 64 + j] * sc + shf) * rinv;
        racc += lrelu_act(v);
    }
    if (curg >= 0) atomicAdd(&sp[curg * 64 + j], racc);
    __syncthreads();
    for (int i = threadIdx.x; i < GG * 64; i += 256)
        if (sp[i] != 0.f) atomicAdd(&pool[i], sp[i]);
}

// ---- readout head ----
__global__ void k_head(const float* __restrict__ pools,
                       const float* __restrict__ cnt,
                       const float* __restrict__ Wr,
                       const float* __restrict__ br,
                       float* __restrict__ out) {
    __shared__ float risk[GG * NCLS];
    int t = threadIdx.x;
    if (t < GG * NCLS) {
        int g = t / NCLS, c = t % NCLS;
        float acc = br[c];
        float icnt = 1.f / cnt[g];
        for (int k = 0; k < (LL + 1) * DIM; ++k) {
            int l = k >> 6, j = k & 63;
            float xc = pools[(l * GG + g) * 64 + j] * icnt;
            acc += xc * Wr[k * NCLS + c];
        }
        risk[t] = acc;
        out[t] = acc;
    }
    __syncthreads();
    if (t < GG) {
        float r0 = risk[t * 2], r1 = risk[t * 2 + 1];
        float m = fmaxf(r0, r1);
        float e0 = expf(r0 - m), e1 = expf(r1 - m);
        float s = e0 + e1;
        out[GG * NCLS + t * 2] = e0 / s;
        out[GG * NCLS + t * 2 + 1] = e1 / s;
        out[2 * GG * NCLS + t] = (r1 > r0) ? 1.f : 0.f;
    }
}

extern "C" void kernel_launch(void* const* d_in, const int* in_sizes, int n_in,
                              void* d_out, int out_size, void* d_ws, size_t ws_size,
                              hipStream_t stream) {
    const float* x     = (const float*)d_in[0];
    const int*   ei    = (const int*)d_in[1];
    const int*   batch = (const int*)d_in[2];
    const float* W     = (const float*)d_in[4];
    const float* asrc  = (const float*)d_in[5];
    const float* adst  = (const float*)d_in[6];
    const float* gamma = (const float*)d_in[8];
    const float* beta  = (const float*)d_in[9];
    const float* Wr    = (const float*)d_in[10];
    const float* br    = (const float*)d_in[11];
    float* out = (float*)d_out;

    char* ws = (char*)d_ws;
    size_t off = 0;
    auto alloc = [&](size_t bytes) {
        void* p = ws + off;
        off += (bytes + 255) & ~(size_t)255;
        return p;
    };
    float*          xcur      = (float*)alloc((size_t)NN * 64 * 4);
    unsigned short* h         = (unsigned short*)alloc((size_t)NN * 64 * 2);
    float*          agg       = (float*)alloc((size_t)NN * 64 * 4);
    float*          es        = (float*)alloc((size_t)NN * 4 * 4);
    float*          ed        = (float*)alloc((size_t)NN * 4 * 4);
    int*            row_start = (int*)alloc((size_t)(NN + 1) * 4);
    int*            ssrc      = (int*)alloc((size_t)EE * 4);
    double*         bnrep     = (double*)alloc((size_t)NREP * 128 * 8);
    float*          scshf     = (float*)alloc(128 * 4);
    // contiguous zero-init group: pools + cnt + deg (one memset)
    float*          pools     = (float*)alloc((size_t)(LL + 1) * GG * 64 * 4);  // 16384 B
    float*          cnt       = (float*)alloc((size_t)GG * 4);                  // 256 B pad
    int*            deg       = (int*)alloc((size_t)NN * 4);
    (void)ws_size; (void)in_sizes; (void)n_in; (void)out_size;

    // CSR-build scratch aliases agg (dead until k_gat_agg overwrites it)
    int* bsum = (int*)agg;
    int* rank = (int*)agg + 1024;

    hipMemsetAsync(pools, 0,
                   (size_t)(LL + 1) * GG * 64 * 4 + 256 + (size_t)NN * 4, stream);

    // ---- build CSR (once; reused by all 3 layers) ----
    k_hist<<<(EE / 4 + 255) / 256, 256, 0, stream>>>(ei, deg, rank);
    k_scan1<<<NSCAN, 256, 0, stream>>>(deg, row_start, bsum);
    k_scan23<<<(NN + 255) / 256, 256, 0, stream>>>(row_start, bsum);
    k_fill<<<8 * FILL_NBLK, 256, 0, stream>>>(ei, rank, row_start, ssrc);

    const int GEMM_GRID = (NN + 63) / 64;

    // ---- layer 0 ----
    k_gemm_t<0><<<GEMM_GRID, 256, 0, stream>>>(x, nullptr, nullptr, batch, nullptr,
                                               W, asrc, adst, nullptr,
                                               h, es, ed, bnrep, pools, cnt);
    k_gat_agg<<<NN / 16, 256, 0, stream>>>(row_start, ssrc, es, ed, h, agg, bnrep);
    k_bn_final<<<1, 64, 0, stream>>>(bnrep, gamma, beta, scshf);

    // ---- layer 1 ----
    k_gemm_t<1><<<GEMM_GRID, 256, 0, stream>>>(x, agg, scshf, batch, cnt,
                                               W + DIM * DIM, asrc + HH * CC, adst + HH * CC,
                                               xcur, h, es, ed, bnrep,
                                               pools + GG * 64, nullptr);
    k_gat_agg<<<NN / 16, 256, 0, stream>>>(row_start, ssrc, es, ed, h, agg, bnrep);
    k_bn_final<<<1, 64, 0, stream>>>(bnrep, gamma + DIM, beta + DIM, scshf);

    // ---- layer 2 (no xcur store: dead after this gemm) ----
    k_gemm_t<2><<<GEMM_GRID, 256, 0, stream>>>(xcur, agg, scshf, batch, cnt,
                                               W + 2 * DIM * DIM, asrc + 2 * HH * CC,
                                               adst + 2 * HH * CC,
                                               nullptr, h, es, ed, bnrep,
                                               pools + 2 * GG * 64, nullptr);
    k_gat_agg<<<NN / 16, 256, 0, stream>>>(row_start, ssrc, es, ed, h, agg, bnrep);
    k_bn_final<<<1, 64, 0, stream>>>(bnrep, gamma + 2 * DIM, beta + 2 * DIM, scshf);

    // ---- final pool of layer-2 activations ----
    k_pool_final<<<NA_BLOCKS, 256, 0, stream>>>(agg, scshf, batch, cnt,
                                                pools + 3 * GG * 64);

    k_head<<<1, 64, 0, stream>>>(pools, cnt, Wr, br, out);
}